// Round 3
// baseline (281.643 us; speedup 1.0000x reference)
//
#include <hip/hip_runtime.h>
#include <math.h>

// Problem constants (B=64, P=2, H=512, W=512)
#define HH 512
#define WW 512
#define BP 128                  // B*P pairs
#define PLANE (HH * WW)         // 262144 elems per (b,p) plane
#define SEG2 32                 // segments per pair (finer than R2's 16)
#define SEG2_F4 2048            // float4 per segment (8192 elems)
#define NPART2 (BP * SEG2)      // 4096 partial records per quantity

// ws float layout: [0,4096) sum, [4096,8192) sumx, [8192,12288) sumy,
// [12288,16384) maxval ; ints at float offset [16384,20480) maxidx. 80 KiB.

// One dispatch, 8192 blocks: [0,4096) = softmax partials on `inp`,
// [4096,8192) = argmax partials on `tgt`. Splitting the streams gives each
// block ONE contiguous 32 KB walk, and 4x oversubscription (8192 blocks vs
// 2048 resident) load-balances the stragglers R2's occupancy=60% exposed.
__global__ __launch_bounds__(256) void dsnt_partial(
    const float* __restrict__ inp, const float* __restrict__ tgt,
    float* __restrict__ wsf, int* __restrict__ wsi)
{
    const int tid  = threadIdx.x;
    const int blk  = blockIdx.x;
    const int lane = tid & 63, wid = tid >> 6;
    const float inv = 1.0f / 512.0f;

    __shared__ float rs[4], rsx[4], rsy[4], rmv[4];
    __shared__ int   rmi[4];

    if (blk < NPART2) {
        // ---- softmax partial sums over input ----
        const int pair = blk >> 5;
        const int seg  = blk & 31;
        const float4* __restrict__ ip =
            (const float4*)(inp + (size_t)pair * PLANE) + seg * SEG2_F4;
        const int segbase = seg * (SEG2_F4 * 4);

        float s = 0.0f, sx = 0.0f, sy = 0.0f;
#pragma unroll
        for (int o = 0; o < 2; ++o) {
            float4 a[4];
#pragma unroll
            for (int j = 0; j < 4; ++j) a[j] = ip[(o * 4 + j) * 256 + tid];
#pragma unroll
            for (int j = 0; j < 4; ++j) {
                const int f = segbase + ((o * 4 + j) * 256 + tid) * 4; // %4==0
                const float yw  = (float)((f >> 9) + 1) * inv;
                const float xw0 = (float)((f & 511) + 1) * inv;
                const float e0 = __expf(a[j].x);
                const float e1 = __expf(a[j].y);
                const float e2 = __expf(a[j].z);
                const float e3 = __expf(a[j].w);
                const float es = e0 + e1 + e2 + e3;
                s  += es;
                sx += es * xw0 + inv * (e1 + 2.0f * e2 + 3.0f * e3);
                sy += es * yw;
            }
        }

#pragma unroll
        for (int off = 32; off > 0; off >>= 1) {
            s  += __shfl_down(s,  off, 64);
            sx += __shfl_down(sx, off, 64);
            sy += __shfl_down(sy, off, 64);
        }
        if (lane == 0) { rs[wid] = s; rsx[wid] = sx; rsy[wid] = sy; }
        __syncthreads();
        if (tid == 0) {
            float fs = rs[0], fsx = rsx[0], fsy = rsy[0];
#pragma unroll
            for (int k = 1; k < 4; ++k) { fs += rs[k]; fsx += rsx[k]; fsy += rsy[k]; }
            wsf[blk]              = fs;
            wsf[NPART2 + blk]     = fsx;
            wsf[2 * NPART2 + blk] = fsy;
        }
    } else {
        // ---- argmax partial over target ----
        const int b2   = blk - NPART2;
        const int pair = b2 >> 5;
        const int seg  = b2 & 31;
        const float4* __restrict__ tp =
            (const float4*)(tgt + (size_t)pair * PLANE) + seg * SEG2_F4;
        const int segbase = seg * (SEG2_F4 * 4);

        float mv = -1.0f;
        int   mi = 0;
#pragma unroll
        for (int o = 0; o < 2; ++o) {
            float4 bb[4];
#pragma unroll
            for (int j = 0; j < 4; ++j) bb[j] = tp[(o * 4 + j) * 256 + tid];
#pragma unroll
            for (int j = 0; j < 4; ++j) {
                const int f = segbase + ((o * 4 + j) * 256 + tid) * 4;
                if (bb[j].x > mv) { mv = bb[j].x; mi = f; }
                if (bb[j].y > mv) { mv = bb[j].y; mi = f + 1; }
                if (bb[j].z > mv) { mv = bb[j].z; mi = f + 2; }
                if (bb[j].w > mv) { mv = bb[j].w; mi = f + 3; }
            }
        }

#pragma unroll
        for (int off = 32; off > 0; off >>= 1) {
            const float ov = __shfl_down(mv, off, 64);
            const int   oi = __shfl_down(mi, off, 64);
            if (ov > mv || (ov == mv && oi < mi)) { mv = ov; mi = oi; }
        }
        if (lane == 0) { rmv[wid] = mv; rmi[wid] = mi; }
        __syncthreads();
        if (tid == 0) {
            float fmv = rmv[0];
            int   fmi = rmi[0];
#pragma unroll
            for (int k = 1; k < 4; ++k)
                if (rmv[k] > fmv || (rmv[k] == fmv && rmi[k] < fmi)) { fmv = rmv[k]; fmi = rmi[k]; }
            wsf[3 * NPART2 + b2] = fmv;
            wsi[b2]              = fmi;
        }
    }
}

__global__ __launch_bounds__(128) void dsnt_finalize(
    const float* __restrict__ wsf, const int* __restrict__ wsi,
    float* __restrict__ out)
{
    __shared__ float px[BP], py[BP], tx[BP], ty[BP];
    __shared__ float wsum[2];
    const int tid = threadIdx.x; // 0..127, one pair per thread

    {
        float s = 0.0f, sx = 0.0f, sy = 0.0f, mv = -1.0f;
        int mi = 0;
#pragma unroll
        for (int k = 0; k < SEG2; ++k) {
            const int i = tid * SEG2 + k;  // segs in ascending index order
            s  += wsf[i];
            sx += wsf[NPART2 + i];
            sy += wsf[2 * NPART2 + i];
            const float v = wsf[3 * NPART2 + i];
            const int  ii = wsi[i];
            if (v > mv || (v == mv && ii < mi)) { mv = v; mi = ii; }
        }
        px[tid] = sx / s;
        py[tid] = sy / s;
        tx[tid] = (float)((mi & 511) + 1) * (1.0f / 512.0f);
        ty[tid] = (float)((mi >> 9) + 1) * (1.0f / 512.0f);
    }
    __syncthreads();

    float term = 0.0f;
    if (tid < 64) {
        const int b = tid;
        const float px0 = px[2 * b], px1 = px[2 * b + 1];
        const float py0 = py[2 * b], py1 = py[2 * b + 1];
        const float tx0 = tx[2 * b], tx1 = tx[2 * b + 1];
        const float ty0 = ty[2 * b], ty1 = ty[2 * b + 1];

        const float ed0 = sqrtf((tx0 - px0) * (tx0 - px0) + (ty0 - py0) * (ty0 - py0));
        const float ed1 = sqrtf((tx1 - px1) * (tx1 - px1) + (ty1 - py1) * (ty1 - py1));

        const float pvx = px0 - px1, pvy = py0 - py1;
        const float tvx = tx0 - tx1, tvy = ty0 - ty1;
        const float pd = sqrtf(pvx * pvx + pvy * pvy);
        const float td = sqrtf(tvx * tvx + tvy * tvy);
        const float dot = pvx * tvx + pvy * tvy;
        const float cosd = 1.0f - cosf(dot / (pd * td));
        term = ed0 + ed1 + fabsf(pd - td) + cosd;
    }

#pragma unroll
    for (int off = 32; off > 0; off >>= 1)
        term += __shfl_down(term, off, 64);
    const int lane = tid & 63, wid = tid >> 6;
    if (lane == 0) wsum[wid] = term;
    __syncthreads();
    if (tid == 0) out[0] = (wsum[0] + wsum[1]) * (1.0f / 64.0f);
}

extern "C" void kernel_launch(void* const* d_in, const int* in_sizes, int n_in,
                              void* d_out, int out_size, void* d_ws, size_t ws_size,
                              hipStream_t stream)
{
    const float* inp = (const float*)d_in[0];
    const float* tgt = (const float*)d_in[1];
    float* out = (float*)d_out;
    float* wsf = (float*)d_ws;
    int*   wsi = (int*)((float*)d_ws + 4 * NPART2);

    dsnt_partial<<<2 * NPART2, 256, 0, stream>>>(inp, tgt, wsf, wsi);
    dsnt_finalize<<<1, 128, 0, stream>>>(wsf, wsi, out);
}

// Round 4
// 279.527 us; speedup vs baseline: 1.0076x; 1.0076x over previous
//
#include <hip/hip_runtime.h>
#include <math.h>

// Problem constants (B=64, P=2, H=512, W=512)
#define HH 512
#define WW 512
#define BP 128                  // B*P pairs
#define PLANE (HH * WW)         // 262144 elems per (b,p) plane
#define SEG2 32                 // segments per pair
#define SEG2_F4 2048            // float4 per segment (8192 elems)
#define NPART2 (BP * SEG2)      // 4096 partial records per quantity

// ws float layout: [0,4096) sum, [4096,8192) sumx, [8192,12288) sumy,
// [12288,16384) maxval ; ints at float offset [16384,20480) maxidx. 80 KiB.

// __launch_bounds__(256, 2): min 2 waves/EU -> VGPR budget ~256. This is the
// point of the round: R1-R3 all had VGPR<=32 because the default occupancy
// target made the scheduler serialize loads (load -> vmcnt(0) -> consume).
// With the budget raised + named variables, 8 global_load_dwordx4 can be in
// flight per wave (8 KB), which per Little's law is enough to stream at HBM
// rate even at reduced occupancy.
__global__ __launch_bounds__(256, 2) void dsnt_partial(
    const float* __restrict__ inp, const float* __restrict__ tgt,
    float* __restrict__ wsf, int* __restrict__ wsi)
{
    const int tid  = threadIdx.x;
    const int blk  = blockIdx.x;
    const int lane = tid & 63, wid = tid >> 6;
    const float inv = 1.0f / 512.0f;

    __shared__ float rs[4], rsx[4], rsy[4], rmv[4];
    __shared__ int   rmi[4];

    if (blk < NPART2) {
        // ---- softmax partial sums over input ----
        const int pair = blk >> 5;
        const int seg  = blk & 31;
        const float4* __restrict__ ip =
            (const float4*)(inp + (size_t)pair * PLANE) + seg * SEG2_F4;
        const int segbase = seg * (SEG2_F4 * 4);

        // 8 named loads issued back-to-back: 8 KB in flight per wave.
        const float4 a0 = ip[0 * 256 + tid];
        const float4 a1 = ip[1 * 256 + tid];
        const float4 a2 = ip[2 * 256 + tid];
        const float4 a3 = ip[3 * 256 + tid];
        const float4 a4 = ip[4 * 256 + tid];
        const float4 a5 = ip[5 * 256 + tid];
        const float4 a6 = ip[6 * 256 + tid];
        const float4 a7 = ip[7 * 256 + tid];

        float s = 0.0f, sx = 0.0f, sy = 0.0f;
        const float4 aa[8] = {a0, a1, a2, a3, a4, a5, a6, a7};
#pragma unroll
        for (int j = 0; j < 8; ++j) {
            const int f = segbase + (j * 256 + tid) * 4;  // %4==0, no row cross
            const float yw  = (float)((f >> 9) + 1) * inv;
            const float xw0 = (float)((f & 511) + 1) * inv;
            const float e0 = __expf(aa[j].x);
            const float e1 = __expf(aa[j].y);
            const float e2 = __expf(aa[j].z);
            const float e3 = __expf(aa[j].w);
            const float es = e0 + e1 + e2 + e3;
            s  += es;
            sx += es * xw0 + inv * (e1 + 2.0f * e2 + 3.0f * e3);
            sy += es * yw;
        }

#pragma unroll
        for (int off = 32; off > 0; off >>= 1) {
            s  += __shfl_down(s,  off, 64);
            sx += __shfl_down(sx, off, 64);
            sy += __shfl_down(sy, off, 64);
        }
        if (lane == 0) { rs[wid] = s; rsx[wid] = sx; rsy[wid] = sy; }
        __syncthreads();
        if (tid == 0) {
            float fs = rs[0], fsx = rsx[0], fsy = rsy[0];
#pragma unroll
            for (int k = 1; k < 4; ++k) { fs += rs[k]; fsx += rsx[k]; fsy += rsy[k]; }
            wsf[blk]              = fs;
            wsf[NPART2 + blk]     = fsx;
            wsf[2 * NPART2 + blk] = fsy;
        }
    } else {
        // ---- argmax partial over target ----
        const int b2   = blk - NPART2;
        const int pair = b2 >> 5;
        const int seg  = b2 & 31;
        const float4* __restrict__ tp =
            (const float4*)(tgt + (size_t)pair * PLANE) + seg * SEG2_F4;
        const int segbase = seg * (SEG2_F4 * 4);

        const float4 t0 = tp[0 * 256 + tid];
        const float4 t1 = tp[1 * 256 + tid];
        const float4 t2 = tp[2 * 256 + tid];
        const float4 t3 = tp[3 * 256 + tid];
        const float4 t4 = tp[4 * 256 + tid];
        const float4 t5 = tp[5 * 256 + tid];
        const float4 t6 = tp[6 * 256 + tid];
        const float4 t7 = tp[7 * 256 + tid];

        float mv = -1.0f;
        int   mi = 0;
        const float4 tt[8] = {t0, t1, t2, t3, t4, t5, t6, t7};
#pragma unroll
        for (int j = 0; j < 8; ++j) {
            const int f = segbase + (j * 256 + tid) * 4;
            if (tt[j].x > mv) { mv = tt[j].x; mi = f; }
            if (tt[j].y > mv) { mv = tt[j].y; mi = f + 1; }
            if (tt[j].z > mv) { mv = tt[j].z; mi = f + 2; }
            if (tt[j].w > mv) { mv = tt[j].w; mi = f + 3; }
        }

#pragma unroll
        for (int off = 32; off > 0; off >>= 1) {
            const float ov = __shfl_down(mv, off, 64);
            const int   oi = __shfl_down(mi, off, 64);
            if (ov > mv || (ov == mv && oi < mi)) { mv = ov; mi = oi; }
        }
        if (lane == 0) { rmv[wid] = mv; rmi[wid] = mi; }
        __syncthreads();
        if (tid == 0) {
            float fmv = rmv[0];
            int   fmi = rmi[0];
#pragma unroll
            for (int k = 1; k < 4; ++k)
                if (rmv[k] > fmv || (rmv[k] == fmv && rmi[k] < fmi)) { fmv = rmv[k]; fmi = rmi[k]; }
            wsf[3 * NPART2 + b2] = fmv;
            wsi[b2]              = fmi;
        }
    }
}

__global__ __launch_bounds__(128) void dsnt_finalize(
    const float* __restrict__ wsf, const int* __restrict__ wsi,
    float* __restrict__ out)
{
    __shared__ float px[BP], py[BP], tx[BP], ty[BP];
    __shared__ float wsum[2];
    const int tid = threadIdx.x; // 0..127, one pair per thread

    {
        float s = 0.0f, sx = 0.0f, sy = 0.0f, mv = -1.0f;
        int mi = 0;
#pragma unroll
        for (int k = 0; k < SEG2; ++k) {
            const int i = tid * SEG2 + k;  // segs in ascending index order
            s  += wsf[i];
            sx += wsf[NPART2 + i];
            sy += wsf[2 * NPART2 + i];
            const float v = wsf[3 * NPART2 + i];
            const int  ii = wsi[i];
            if (v > mv || (v == mv && ii < mi)) { mv = v; mi = ii; }
        }
        px[tid] = sx / s;
        py[tid] = sy / s;
        tx[tid] = (float)((mi & 511) + 1) * (1.0f / 512.0f);
        ty[tid] = (float)((mi >> 9) + 1) * (1.0f / 512.0f);
    }
    __syncthreads();

    float term = 0.0f;
    if (tid < 64) {
        const int b = tid;
        const float px0 = px[2 * b], px1 = px[2 * b + 1];
        const float py0 = py[2 * b], py1 = py[2 * b + 1];
        const float tx0 = tx[2 * b], tx1 = tx[2 * b + 1];
        const float ty0 = ty[2 * b], ty1 = ty[2 * b + 1];

        const float ed0 = sqrtf((tx0 - px0) * (tx0 - px0) + (ty0 - py0) * (ty0 - py0));
        const float ed1 = sqrtf((tx1 - px1) * (tx1 - px1) + (ty1 - py1) * (ty1 - py1));

        const float pvx = px0 - px1, pvy = py0 - py1;
        const float tvx = tx0 - tx1, tvy = ty0 - ty1;
        const float pd = sqrtf(pvx * pvx + pvy * pvy);
        const float td = sqrtf(tvx * tvx + tvy * tvy);
        const float dot = pvx * tvx + pvy * tvy;
        const float cosd = 1.0f - cosf(dot / (pd * td));
        term = ed0 + ed1 + fabsf(pd - td) + cosd;
    }

#pragma unroll
    for (int off = 32; off > 0; off >>= 1)
        term += __shfl_down(term, off, 64);
    const int lane = tid & 63, wid = tid >> 6;
    if (lane == 0) wsum[wid] = term;
    __syncthreads();
    if (tid == 0) out[0] = (wsum[0] + wsum[1]) * (1.0f / 64.0f);
}

extern "C" void kernel_launch(void* const* d_in, const int* in_sizes, int n_in,
                              void* d_out, int out_size, void* d_ws, size_t ws_size,
                              hipStream_t stream)
{
    const float* inp = (const float*)d_in[0];
    const float* tgt = (const float*)d_in[1];
    float* out = (float*)d_out;
    float* wsf = (float*)d_ws;
    int*   wsi = (int*)((float*)d_ws + 4 * NPART2);

    dsnt_partial<<<2 * NPART2, 256, 0, stream>>>(inp, tgt, wsf, wsi);
    dsnt_finalize<<<1, 128, 0, stream>>>(wsf, wsi, out);
}